// Round 9
// baseline (508.230 us; speedup 1.0000x reference)
//
#include <hip/hip_runtime.h>

#define B_ 512
#define S_ 512
#define E_ 128
#define H_ 100
#define T_ 64
#define BS_ (B_*S_)
#define NPROD 4096
#define MAGIC 0x1F2E3D4Cu

typedef __attribute__((ext_vector_type(8))) short bf16x8;
typedef __attribute__((ext_vector_type(4))) float f32x4;
typedef __attribute__((ext_vector_type(2))) float f32x2;
union U16x4 { uint4 u; bf16x8 s; };

__device__ __forceinline__ unsigned f2bf1(float x){
    unsigned u = __float_as_uint(x);
    return (u + 0x7FFFu + ((u>>16)&1u)) >> 16;
}
__device__ __forceinline__ float bf2f(unsigned short h){
    return __uint_as_float(((unsigned)h)<<16);
}
__device__ __forceinline__ float rfl_f(float x){
    return __uint_as_float(__builtin_amdgcn_readfirstlane(__float_as_uint(x)));
}

// ---------------------------------------------------------------------------
// Prep: W1/W2 bf16 MFMA B-fragment images (44 parallel blocks).
// ---------------------------------------------------------------------------
__global__ __launch_bounds__(64) void prep_kernel(
    const float* __restrict__ W1, const float* __restrict__ W2,
    uint4* __restrict__ W1f, uint4* __restrict__ W2f)
{
    const int idx = blockIdx.x*64 + threadIdx.x;
    if (idx < 7*4*64) {
        int lane = idx & 63, kt = (idx>>6)&3, nt = idx>>8;
        int n = nt*16 + (lane&15);
        int kb = kt*32 + (lane>>4)*8;
        unsigned wv[4];
        #pragma unroll
        for (int p = 0; p < 4; ++p) {
            float v0 = (n < H_) ? W1[(kb+2*p  )*H_ + n] : 0.f;
            float v1 = (n < H_) ? W1[(kb+2*p+1)*H_ + n] : 0.f;
            wv[p] = f2bf1(v0) | (f2bf1(v1) << 16);
        }
        W1f[idx] = make_uint4(wv[0],wv[1],wv[2],wv[3]);
    } else {
        int id2 = idx - 7*4*64;
        int lane = id2 & 63, kt = (id2>>6)&3, nt = id2>>8;
        int n = nt*16 + (lane&15);
        int kb = kt*32 + (lane>>4)*8;
        unsigned wv[4];
        #pragma unroll
        for (int p = 0; p < 4; ++p) {
            int k0 = kb+2*p, k1 = kb+2*p+1;
            float v0 = (k0 < H_) ? W2[k0*T_ + n] : 0.f;
            float v1 = (k1 < H_) ? W2[k1*T_ + n] : 0.f;
            wv[p] = f2bf1(v0) | (f2bf1(v1) << 16);
        }
        W2f[id2] = make_uint4(wv[0],wv[1],wv[2],wv[3]);
    }
}

// ---------------------------------------------------------------------------
// FUSED producer/consumer kernel.
//  blocks [0, 4096): producer (mlp). blockIdx = k*512 + b -> em chunk k
//    (64 rows) of batch b. Chunk-major order => chunk-0 of every batch done
//    early; flag[b*8+k] released (agent scope) after stores drain.
//  blocks [4096, 4608): consumer (crf scan, 1 wave). Waits flag[b*8+chunk]
//    before ANY em read of that chunk; numerator accumulated from the staged
//    LDS chunk (no upfront em pass).
// ---------------------------------------------------------------------------
__global__ __launch_bounds__(256, 3) void fused_kernel(
    const int* __restrict__ inputs, const int* __restrict__ tags,
    const float* __restrict__ tbl,
    const float* __restrict__ b1, const float* __restrict__ b2,
    const uint4* __restrict__ W1f, const uint4* __restrict__ W2f,
    const float* __restrict__ start_trans, const float* __restrict__ end_trans,
    const float* __restrict__ trans,
    unsigned short* __restrict__ em, unsigned* __restrict__ flags,
    float* __restrict__ out)
{
    __shared__ uint4 sbuf[1024];   // producer: frag/transpose; consumer: sem+pbuf

    if (blockIdx.x < NPROD) {
        // =================== PRODUCER (mlp, r8 math) ===================
        const int tid  = threadIdx.x;
        const int lane = tid & 63;
        const int w    = tid >> 6;
        const int col  = lane & 15;
        const int hi   = lane >> 4;
        const int rowin = hi * 4;      // C/D: col=lane&15, row=(lane>>4)*4+reg
        const int g = (blockIdx.x % 512) * 8 + (blockIdx.x / 512);

        const int rg = g*64 + w*16 + col;
        const int i0 = inputs[rg*3+0], i1 = inputs[rg*3+1], i2 = inputs[rg*3+2];
        const float4* r0 = (const float4*)tbl + (size_t)i0*(E_/4);
        const float4* r1 = (const float4*)tbl + (size_t)i1*(E_/4);
        const float4* r2 = (const float4*)tbl + (size_t)i2*(E_/4);

        U16x4 a[4];
        #pragma unroll
        for (int kt = 0; kt < 4; ++kt) {
            int fo = kt*8 + hi*2;
            float4 x0 = r0[fo], y0 = r0[fo+1];
            float4 x1 = r1[fo], y1 = r1[fo+1];
            float4 x2 = r2[fo], y2 = r2[fo+1];
            float v0 = x0.x+x1.x+x2.x, v1 = x0.y+x1.y+x2.y;
            float v2 = x0.z+x1.z+x2.z, v3 = x0.w+x1.w+x2.w;
            float v4 = y0.x+y1.x+y2.x, v5 = y0.y+y1.y+y2.y;
            float v6 = y0.z+y1.z+y2.z, v7 = y0.w+y1.w+y2.w;
            a[kt].u = make_uint4(f2bf1(v0)|(f2bf1(v1)<<16), f2bf1(v2)|(f2bf1(v3)<<16),
                                 f2bf1(v4)|(f2bf1(v5)<<16), f2bf1(v6)|(f2bf1(v7)<<16));
        }

        f32x4 acc1[7];
        #pragma unroll
        for (int nt = 0; nt < 7; ++nt) {
            int n = nt*16 + col;
            float bv = (n < H_) ? b1[n] : 0.f;
            f32x4 c; c[0]=bv; c[1]=bv; c[2]=bv; c[3]=bv;
            #pragma unroll
            for (int k = 0; k < 4; ++k) {
                U16x4 bfr; bfr.u = W1f[(nt*4+k)*64 + lane];
                c = __builtin_amdgcn_mfma_f32_16x16x32_bf16(a[k].s, bfr.s, c, 0,0,0);
            }
            acc1[nt] = c;
        }
        #pragma unroll
        for (int nt = 0; nt < 7; ++nt)
            #pragma unroll
            for (int rr = 0; rr < 4; ++rr) {
                float x = acc1[nt][rr];
                acc1[nt][rr] = 1.f - 2.f/(__expf(2.f*x)+1.f);
            }

        if (lane >= 32) sbuf[(w*4+3)*64 + lane] = make_uint4(0,0,0,0);
        unsigned short* A2h = (unsigned short*)sbuf;
        #pragma unroll
        for (int nt = 0; nt < 7; ++nt)
            #pragma unroll
            for (int rr = 0; rr < 4; ++rr) {
                int k2 = nt*16 + col;
                int kt2 = k2 >> 5, g2 = (k2>>3)&3, i2v = k2&7;
                int u4idx = (w*4 + kt2)*64 + g2*16 + (rowin + rr);
                A2h[u4idx*8 + i2v] = (unsigned short)f2bf1(acc1[nt][rr]);
            }
        __builtin_amdgcn_wave_barrier();

        U16x4 a2[4];
        #pragma unroll
        for (int k = 0; k < 4; ++k) a2[k].u = sbuf[(w*4+k)*64 + lane];
        __builtin_amdgcn_wave_barrier();

        unsigned short* tbuf = (unsigned short*)(sbuf + (size_t)w*256);
        #pragma unroll
        for (int nt2 = 0; nt2 < 4; ++nt2) {
            float bv = b2[nt2*16 + col];
            f32x4 c; c[0]=bv; c[1]=bv; c[2]=bv; c[3]=bv;
            #pragma unroll
            for (int k = 0; k < 4; ++k) {
                U16x4 bfr; bfr.u = W2f[(nt2*4+k)*64 + lane];
                c = __builtin_amdgcn_mfma_f32_16x16x32_bf16(a2[k].s, bfr.s, c, 0,0,0);
            }
            #pragma unroll
            for (int rr = 0; rr < 4; ++rr)
                tbuf[(rowin+rr)*72 + nt2*16 + col] = (unsigned short)f2bf1(c[rr]);
        }
        __builtin_amdgcn_wave_barrier();

        {
            const int rl = lane >> 2;
            const int ch = (lane & 3) * 2;
            const uint4* t4 = (const uint4*)tbuf;
            uint4 u0 = t4[rl*9 + ch];
            uint4 u1 = t4[rl*9 + ch + 1];
            size_t rowg = (size_t)(g*64 + w*16 + rl);
            uint4* dst = (uint4*)(em + rowg*T_);
            dst[ch]   = u0;
            dst[ch+1] = u1;
        }

        __syncthreads();   // drains vmcnt(0) for all waves before barrier
        if (tid == 0)
            __hip_atomic_store(&flags[g], MAGIC, __ATOMIC_RELEASE,
                               __HIP_MEMORY_SCOPE_AGENT);
        return;
    }

    // ===================== CONSUMER (crf scan, 1 wave) =====================
    if (threadIdx.x >= 64) return;
    const int b = blockIdx.x - NPROD;
    const int j = threadIdx.x;
    const unsigned short* em_b = em + (size_t)b*S_*T_;
    const int* tags_b = tags + b*S_;
    const int* in_b = inputs + (size_t)b*S_*3;

    unsigned short (*sem)[512] = (unsigned short (*)[512])sbuf;  // 2 x 1 KB
    float* pbuf = (float*)(sbuf + 128);                          // 256 B

    // mask ballots (inputs only — always valid)
    unsigned long long mball[8];
    int mcount = 0;
    #pragma unroll
    for (int gg = 0; gg < 8; ++gg) {
        int t = gg*64 + j;
        int a0 = in_b[t*3+0], a1 = in_b[t*3+1], a2 = in_b[t*3+2];
        bool mk = ((a0 | a1 | a2) != 0);
        mball[gg] = __ballot(mk);
        mcount += __popcll(mball[gg]) ? 0 : 0;   // popcount below (uniform)
    }
    #pragma unroll
    for (int gg = 0; gg < 8; ++gg) mcount += __popcll(mball[gg]);
    const int tag0 = tags_b[0];
    int se = mcount - 1; if (se < 0) se = 0;
    const int last_tag = tags_b[se];
    mball[0] &= ~1ull;                 // t=0 is not a scan step

    // E column j as f32x2 pairs
    f32x2 E2[32];
    #pragma unroll
    for (int i = 0; i < 32; ++i) {
        f32x2 e; e.x = __expf(trans[(2*i)*T_ + j]); e.y = __expf(trans[(2*i+1)*T_ + j]);
        E2[i] = e;
    }

    auto wait_flag = [&](int idx){
        while (__hip_atomic_load(&flags[idx], __ATOMIC_ACQUIRE,
                                 __HIP_MEMORY_SCOPE_AGENT) != MAGIC)
            __builtin_amdgcn_s_sleep(2);
    };

    wait_flag(b*8 + 0);
    const uint4* em4 = (const uint4*)em_b;
    uint4 gbuf = em4[j];
    ((uint4*)sem[0])[j] = gbuf;
    __builtin_amdgcn_wave_barrier();
    float eg[8];
    #pragma unroll
    for (int c = 0; c < 8; ++c) eg[c] = __expf(bf2f(sem[0][c*T_ + j]));

    float x0v = start_trans[j] + bf2f(sem[0][j]);   // em[0][j] from LDS
    float ls = rfl_f(x0v);
    float a = __expf(x0v - ls);
    float np = 0.f;                                 // numerator partial
    gbuf = em4[64 + j];                             // group 1 (chunk 0)

    for (int g = 0; g < 64; ++g) {
        unsigned short raw16[8];
        if (g < 63) {
            ((uint4*)sem[(g+1)&1])[j] = gbuf;
            __builtin_amdgcn_wave_barrier();
            #pragma unroll
            for (int c = 0; c < 8; ++c) raw16[c] = sem[(g+1)&1][c*T_ + j];
            if (g < 62) {
                int ng = g + 2;
                if ((ng & 7) == 0) wait_flag(b*8 + (ng >> 3));
                gbuf = em4[ng*64 + j];
            }
        }
        const unsigned mg = (unsigned)((mball[g>>3] >> ((g&7)*8)) & 0xFFull);

        // numerator terms for this group's timesteps (from staged LDS chunk)
        {
            const unsigned short* scur = sem[g&1];
            if (j < 8) {
                int t = g*8 + j;
                if (t >= 1 && ((mball[t>>6] >> (t&63)) & 1ull)) {
                    int tp = tags_b[t-1], tc = tags_b[t];
                    np += trans[tp*T_ + tc] + bf2f(scur[j*T_ + tc]);
                }
                if (t == 0) np += start_trans[tag0] + bf2f(scur[tag0]);
            }
        }

        #pragma unroll
        for (int c = 0; c < 8; ++c) {
            pbuf[j] = a;                           // broadcast UNSCALED a
            __builtin_amdgcn_wave_barrier();
            float s    = rfl_f(a);
            float sinv = __builtin_amdgcn_rcpf(s);
            float logs = __logf(s);
            float keep = a * sinv;
            float dmul = eg[c] * sinv;
            const float4* pb4 = (const float4*)pbuf;
            f32x2 ac0={0.f,0.f}, ac1={0.f,0.f}, ac2={0.f,0.f}, ac3={0.f,0.f};
            #pragma unroll
            for (int q = 0; q < 4; ++q) {
                float4 A0 = pb4[4*q+0], A1 = pb4[4*q+1], A2v = pb4[4*q+2], A3 = pb4[4*q+3];
                f32x2 p0; p0.x=A0.x; p0.y=A0.y;  f32x2 p1; p1.x=A0.z; p1.y=A0.w;
                f32x2 p2; p2.x=A1.x; p2.y=A1.y;  f32x2 p3; p3.x=A1.z; p3.y=A1.w;
                f32x2 p4; p4.x=A2v.x;p4.y=A2v.y; f32x2 p5; p5.x=A2v.z;p5.y=A2v.w;
                f32x2 p6; p6.x=A3.x; p6.y=A3.y;  f32x2 p7; p7.x=A3.z; p7.y=A3.w;
                ac0 = p0*E2[8*q+0] + ac0;  ac1 = p1*E2[8*q+1] + ac1;
                ac2 = p2*E2[8*q+2] + ac2;  ac3 = p3*E2[8*q+3] + ac3;
                ac0 = p4*E2[8*q+4] + ac0;  ac1 = p5*E2[8*q+5] + ac1;
                ac2 = p6*E2[8*q+6] + ac2;  ac3 = p7*E2[8*q+7] + ac3;
            }
            f32x2 st = (ac0+ac1)+(ac2+ac3);
            float dot = st.x + st.y;
            float cand = dot * dmul;
            a = ((mg >> c) & 1u) ? cand : keep;
            ls += logs;
            __builtin_amdgcn_wave_barrier();
        }
        if (g < 63) {
            #pragma unroll
            for (int c = 0; c < 8; ++c) eg[c] = __expf(bf2f(raw16[c]));
        }
    }

    // denominator + numerator reduce
    float x = a * __expf(end_trans[j]);
    #pragma unroll
    for (int off = 32; off >= 1; off >>= 1) x  += __shfl_xor(x,  off, 64);
    #pragma unroll
    for (int off = 32; off >= 1; off >>= 1) np += __shfl_xor(np, off, 64);
    if (j == 0) out[b] = ls + __logf(x) - (np + end_trans[last_tag]);
}

// ---------------------------------------------------------------------------
extern "C" void kernel_launch(void* const* d_in, const int* in_sizes, int n_in,
                              void* d_out, int out_size, void* d_ws, size_t ws_size,
                              hipStream_t stream) {
    const int*   inputs      = (const int*)  d_in[0];
    const int*   tags        = (const int*)  d_in[1];
    const float* emb_table   = (const float*)d_in[2];
    const float* W1          = (const float*)d_in[3];
    const float* b1          = (const float*)d_in[4];
    const float* W2          = (const float*)d_in[5];
    const float* b2          = (const float*)d_in[6];
    const float* start_trans = (const float*)d_in[7];
    const float* end_trans   = (const float*)d_in[8];
    const float* transitions = (const float*)d_in[9];
    float* out = (float*)d_out;

    // ws layout: em bf16 (32 MiB) | W1f (28 KB) | W2f (16 KB) | flags (16 KB)
    unsigned short* em = (unsigned short*)d_ws;
    uint4* W1f = (uint4*)((char*)d_ws + (size_t)BS_*T_*2);
    uint4* W2f = W1f + 7*4*64;
    unsigned* flags = (unsigned*)((char*)d_ws + (size_t)BS_*T_*2 + 28672 + 16384);

    prep_kernel<<<dim3((7*4*64 + 4*4*64)/64), dim3(64), 0, stream>>>(W1, W2, W1f, W2f);
    fused_kernel<<<dim3(NPROD + B_), dim3(256), 0, stream>>>(
        inputs, tags, emb_table, b1, b2, W1f, W2f,
        start_trans, end_trans, transitions, em, flags, out);
}

// Round 10
// 324.330 us; speedup vs baseline: 1.5670x; 1.5670x over previous
//
#include <hip/hip_runtime.h>

#define B_ 512
#define S_ 512
#define E_ 128
#define H_ 100
#define T_ 64
#define V_ 100000
#define BS_ (B_*S_)

typedef __attribute__((ext_vector_type(8))) short bf16x8;
typedef __attribute__((ext_vector_type(4))) float f32x4;
typedef __attribute__((ext_vector_type(2))) float f32x2;
union U16x4 { uint4 u; bf16x8 s; };

__device__ __forceinline__ unsigned f2bf1(float x){
    unsigned u = __float_as_uint(x);
    return (u + 0x7FFFu + ((u>>16)&1u)) >> 16;
}
__device__ __forceinline__ float bf2f(unsigned short h){
    return __uint_as_float(((unsigned)h)<<16);
}
__device__ __forceinline__ float rfl_f(float x){
    return __uint_as_float(__builtin_amdgcn_readfirstlane(__float_as_uint(x)));
}
// sum three packed-bf16 pairs in fp32, round-pack back to bf16x2
__device__ __forceinline__ unsigned addpack3(unsigned a, unsigned b, unsigned c){
    float lo = __uint_as_float(a<<16) + __uint_as_float(b<<16) + __uint_as_float(c<<16);
    float hi = __uint_as_float(a&0xFFFF0000u) + __uint_as_float(b&0xFFFF0000u)
             + __uint_as_float(c&0xFFFF0000u);
    return f2bf1(lo) | (f2bf1(hi)<<16);
}

// ---------------------------------------------------------------------------
// prep_tbl: fp32 emb table -> bf16 copy (halves mlp gather bytes).
// ---------------------------------------------------------------------------
__global__ __launch_bounds__(256) void prep_tbl(
    const float* __restrict__ tbl, uint2* __restrict__ tblh)
{
    int idx = blockIdx.x*256 + threadIdx.x;     // one float4 -> 4 bf16
    if (idx < (V_*E_)/4) {
        float4 v = ((const float4*)tbl)[idx];
        uint2 o;
        o.x = f2bf1(v.x) | (f2bf1(v.y)<<16);
        o.y = f2bf1(v.z) | (f2bf1(v.w)<<16);
        tblh[idx] = o;
    }
}

// ---------------------------------------------------------------------------
// prep_w: W1/W2 bf16 MFMA B-fragment images (44 parallel blocks).
// ---------------------------------------------------------------------------
__global__ __launch_bounds__(64) void prep_w(
    const float* __restrict__ W1, const float* __restrict__ W2,
    uint4* __restrict__ W1f, uint4* __restrict__ W2f)
{
    const int idx = blockIdx.x*64 + threadIdx.x;
    if (idx < 7*4*64) {
        int lane = idx & 63, kt = (idx>>6)&3, nt = idx>>8;
        int n = nt*16 + (lane&15);
        int kb = kt*32 + (lane>>4)*8;
        unsigned wv[4];
        #pragma unroll
        for (int p = 0; p < 4; ++p) {
            float v0 = (n < H_) ? W1[(kb+2*p  )*H_ + n] : 0.f;
            float v1 = (n < H_) ? W1[(kb+2*p+1)*H_ + n] : 0.f;
            wv[p] = f2bf1(v0) | (f2bf1(v1) << 16);
        }
        W1f[idx] = make_uint4(wv[0],wv[1],wv[2],wv[3]);
    } else {
        int id2 = idx - 7*4*64;
        int lane = id2 & 63, kt = (id2>>6)&3, nt = id2>>8;
        int n = nt*16 + (lane&15);
        int kb = kt*32 + (lane>>4)*8;
        unsigned wv[4];
        #pragma unroll
        for (int p = 0; p < 4; ++p) {
            int k0 = kb+2*p, k1 = kb+2*p+1;
            float v0 = (k0 < H_) ? W2[k0*T_ + n] : 0.f;
            float v1 = (k1 < H_) ? W2[k1*T_ + n] : 0.f;
            wv[p] = f2bf1(v0) | (f2bf1(v1) << 16);
        }
        W2f[id2] = make_uint4(wv[0],wv[1],wv[2],wv[3]);
    }
}

// ---------------------------------------------------------------------------
// MLP: gathers from the bf16 table (12 uint4 loads/row-set, was 24 float4).
// Occupancy 6 blocks/CU (96KB LDS, VGPR<=85; was 84 at bounds(256,4)).
// ---------------------------------------------------------------------------
__global__ __launch_bounds__(256, 6) void mlp_kernel(
    const int* __restrict__ inputs, const unsigned short* __restrict__ tblh,
    const float* __restrict__ b1, const float* __restrict__ b2,
    const uint4* __restrict__ W1f, const uint4* __restrict__ W2f,
    unsigned short* __restrict__ em)
{
    __shared__ uint4 sA2[1024];    // 16 KB; per-wave: A2 frags, then out-transpose

    const int tid  = threadIdx.x;
    const int lane = tid & 63;
    const int w    = tid >> 6;
    const int col  = lane & 15;
    const int hi   = lane >> 4;
    const int rowin = hi * 4;      // C/D: col=lane&15, row=(lane>>4)*4+reg (m89)

    const int rg = blockIdx.x*64 + w*16 + col;
    const int i0 = inputs[rg*3+0], i1 = inputs[rg*3+1], i2 = inputs[rg*3+2];
    const unsigned short* tr0 = tblh + (size_t)i0*E_;
    const unsigned short* tr1 = tblh + (size_t)i1*E_;
    const unsigned short* tr2 = tblh + (size_t)i2*E_;

    // A fragments: lane needs k = kt*32 + hi*8 + 0..7 -> one uint4 per row
    U16x4 a[4];
    #pragma unroll
    for (int kt = 0; kt < 4; ++kt) {
        int off = kt*32 + hi*8;
        uint4 u0 = *(const uint4*)(tr0 + off);
        uint4 u1 = *(const uint4*)(tr1 + off);
        uint4 u2 = *(const uint4*)(tr2 + off);
        a[kt].u = make_uint4(addpack3(u0.x,u1.x,u2.x), addpack3(u0.y,u1.y,u2.y),
                             addpack3(u0.z,u1.z,u2.z), addpack3(u0.w,u1.w,u2.w));
    }

    f32x4 acc1[7];
    #pragma unroll
    for (int nt = 0; nt < 7; ++nt) {
        int n = nt*16 + col;
        float bv = (n < H_) ? b1[n] : 0.f;
        f32x4 c; c[0]=bv; c[1]=bv; c[2]=bv; c[3]=bv;
        #pragma unroll
        for (int k = 0; k < 4; ++k) {
            U16x4 bfr; bfr.u = W1f[(nt*4+k)*64 + lane];
            c = __builtin_amdgcn_mfma_f32_16x16x32_bf16(a[k].s, bfr.s, c, 0,0,0);
        }
        acc1[nt] = c;
    }
    #pragma unroll
    for (int nt = 0; nt < 7; ++nt)
        #pragma unroll
        for (int rr = 0; rr < 4; ++rr) {
            float x = acc1[nt][rr];
            acc1[nt][rr] = 1.f - 2.f/(__expf(2.f*x)+1.f);
        }

    if (lane >= 32) sA2[(w*4+3)*64 + lane] = make_uint4(0,0,0,0);
    unsigned short* A2h = (unsigned short*)sA2;
    #pragma unroll
    for (int nt = 0; nt < 7; ++nt)
        #pragma unroll
        for (int rr = 0; rr < 4; ++rr) {
            int k2 = nt*16 + col;
            int kt2 = k2 >> 5, g2 = (k2>>3)&3, i2v = k2&7;
            int u4idx = (w*4 + kt2)*64 + g2*16 + (rowin + rr);
            A2h[u4idx*8 + i2v] = (unsigned short)f2bf1(acc1[nt][rr]);
        }
    __builtin_amdgcn_wave_barrier();

    U16x4 a2[4];
    #pragma unroll
    for (int k = 0; k < 4; ++k) a2[k].u = sA2[(w*4+k)*64 + lane];
    __builtin_amdgcn_wave_barrier();

    // out-transpose: 16 rows x 72 shorts (144B stride) in wave quarter
    unsigned short* tbuf = (unsigned short*)(sA2 + (size_t)w*256);
    #pragma unroll
    for (int nt2 = 0; nt2 < 4; ++nt2) {
        float bv = b2[nt2*16 + col];
        f32x4 c; c[0]=bv; c[1]=bv; c[2]=bv; c[3]=bv;
        #pragma unroll
        for (int k = 0; k < 4; ++k) {
            U16x4 bfr; bfr.u = W2f[(nt2*4+k)*64 + lane];
            c = __builtin_amdgcn_mfma_f32_16x16x32_bf16(a2[k].s, bfr.s, c, 0,0,0);
        }
        #pragma unroll
        for (int rr = 0; rr < 4; ++rr)
            tbuf[(rowin+rr)*72 + nt2*16 + col] = (unsigned short)f2bf1(c[rr]);
    }
    __builtin_amdgcn_wave_barrier();

    {
        const int rl = lane >> 2;
        const int ch = (lane & 3) * 2;
        const uint4* t4 = (const uint4*)tbuf;
        uint4 u0 = t4[rl*9 + ch];
        uint4 u1 = t4[rl*9 + ch + 1];
        size_t rowg = (size_t)(blockIdx.x*64 + w*16 + rl);
        uint4* dst = (uint4*)(em + rowg*T_);
        dst[ch]   = u0;
        dst[ch+1] = u1;
    }
}

// ---------------------------------------------------------------------------
// CRF scan — EXACT round-4/8 kernel (measured 163 us).
// ---------------------------------------------------------------------------
__global__ __launch_bounds__(64) void crf_kernel(
    const int* __restrict__ inputs, const int* __restrict__ tags,
    const unsigned short* __restrict__ em, const float* __restrict__ start_trans,
    const float* __restrict__ end_trans, const float* __restrict__ trans,
    float* __restrict__ out)
{
    __shared__ unsigned short sem[2][8*T_];   // 2 x 1 KB em staging
    __shared__ float pbuf[T_];

    const int b = blockIdx.x;
    const int j = threadIdx.x;
    const unsigned short* em_b = em + (size_t)b*S_*T_;
    const int* tags_b = tags + b*S_;
    const int* in_b = inputs + (size_t)b*S_*3;

    unsigned long long mball[8];
    float partial = 0.f;
    #pragma unroll
    for (int g = 0; g < 8; ++g) {
        int t = g*64 + j;
        int a0 = in_b[t*3+0], a1 = in_b[t*3+1], a2 = in_b[t*3+2];
        bool mk = ((a0 | a1 | a2) != 0);
        mball[g] = __ballot(mk);
        if (t >= 1 && mk) {
            int tp = tags_b[t-1], tc = tags_b[t];
            partial += trans[tp*T_ + tc] + bf2f(em_b[(size_t)t*T_ + tc]);
        }
    }
    int mcount = 0;
    #pragma unroll
    for (int g = 0; g < 8; ++g) mcount += __popcll(mball[g]);
    mball[0] &= ~1ull;
    #pragma unroll
    for (int off = 32; off >= 1; off >>= 1) partial += __shfl_xor(partial, off, 64);
    const int tag0 = tags_b[0];
    int se = mcount - 1; if (se < 0) se = 0;
    const int last_tag = tags_b[se];
    const float numer = partial + start_trans[tag0] + bf2f(em_b[tag0]) + end_trans[last_tag];

    f32x2 E2[32];
    #pragma unroll
    for (int i = 0; i < 32; ++i) {
        f32x2 e; e.x = __expf(trans[(2*i)*T_ + j]); e.y = __expf(trans[(2*i+1)*T_ + j]);
        E2[i] = e;
    }

    float x0v = start_trans[j] + bf2f(em_b[j]);
    float ls = rfl_f(x0v);
    float a = __expf(x0v - ls);

    const uint4* em4 = (const uint4*)em_b;
    uint4 gbuf = em4[j];
    ((uint4*)sem[0])[j] = gbuf;
    __builtin_amdgcn_wave_barrier();
    float eg[8];
    #pragma unroll
    for (int c = 0; c < 8; ++c) eg[c] = __expf(bf2f(sem[0][c*T_ + j]));
    gbuf = em4[64 + j];

    for (int g = 0; g < 64; ++g) {
        unsigned short raw16[8];
        if (g < 63) {
            ((uint4*)sem[(g+1)&1])[j] = gbuf;
            __builtin_amdgcn_wave_barrier();
            #pragma unroll
            for (int c = 0; c < 8; ++c) raw16[c] = sem[(g+1)&1][c*T_ + j];
            if (g < 62) gbuf = em4[(g+2)*64 + j];
        }
        const unsigned mg = (unsigned)((mball[g>>3] >> ((g&7)*8)) & 0xFFull);

        #pragma unroll
        for (int c = 0; c < 8; ++c) {
            pbuf[j] = a;                           // broadcast UNSCALED a
            __builtin_amdgcn_wave_barrier();
            float s    = rfl_f(a);
            float sinv = __builtin_amdgcn_rcpf(s);
            float logs = __logf(s);
            float keep = a * sinv;
            float dmul = eg[c] * sinv;
            const float4* pb4 = (const float4*)pbuf;
            f32x2 ac0={0.f,0.f}, ac1={0.f,0.f}, ac2={0.f,0.f}, ac3={0.f,0.f};
            #pragma unroll
            for (int q = 0; q < 4; ++q) {
                float4 A0 = pb4[4*q+0], A1 = pb4[4*q+1], A2v = pb4[4*q+2], A3 = pb4[4*q+3];
                f32x2 p0; p0.x=A0.x; p0.y=A0.y;  f32x2 p1; p1.x=A0.z; p1.y=A0.w;
                f32x2 p2; p2.x=A1.x; p2.y=A1.y;  f32x2 p3; p3.x=A1.z; p3.y=A1.w;
                f32x2 p4; p4.x=A2v.x;p4.y=A2v.y; f32x2 p5; p5.x=A2v.z;p5.y=A2v.w;
                f32x2 p6; p6.x=A3.x; p6.y=A3.y;  f32x2 p7; p7.x=A3.z; p7.y=A3.w;
                ac0 = p0*E2[8*q+0] + ac0;  ac1 = p1*E2[8*q+1] + ac1;
                ac2 = p2*E2[8*q+2] + ac2;  ac3 = p3*E2[8*q+3] + ac3;
                ac0 = p4*E2[8*q+4] + ac0;  ac1 = p5*E2[8*q+5] + ac1;
                ac2 = p6*E2[8*q+6] + ac2;  ac3 = p7*E2[8*q+7] + ac3;
            }
            f32x2 st = (ac0+ac1)+(ac2+ac3);
            float dot = st.x + st.y;
            float cand = dot * dmul;
            a = ((mg >> c) & 1u) ? cand : keep;
            ls += logs;
            __builtin_amdgcn_wave_barrier();
        }
        if (g < 63) {
            #pragma unroll
            for (int c = 0; c < 8; ++c) eg[c] = __expf(bf2f(raw16[c]));
        }
    }

    float x = a * __expf(end_trans[j]);
    #pragma unroll
    for (int off = 32; off >= 1; off >>= 1) x += __shfl_xor(x, off, 64);
    if (j == 0) out[b] = ls + __logf(x) - numer;
}

// ---------------------------------------------------------------------------
extern "C" void kernel_launch(void* const* d_in, const int* in_sizes, int n_in,
                              void* d_out, int out_size, void* d_ws, size_t ws_size,
                              hipStream_t stream) {
    const int*   inputs      = (const int*)  d_in[0];
    const int*   tags        = (const int*)  d_in[1];
    const float* emb_table   = (const float*)d_in[2];
    const float* W1          = (const float*)d_in[3];
    const float* b1          = (const float*)d_in[4];
    const float* W2          = (const float*)d_in[5];
    const float* b2          = (const float*)d_in[6];
    const float* start_trans = (const float*)d_in[7];
    const float* end_trans   = (const float*)d_in[8];
    const float* transitions = (const float*)d_in[9];
    float* out = (float*)d_out;

    // ws: em bf16 (32 MiB) | W1f 28KB | W2f 16KB | tblh bf16 (25.6 MB)
    unsigned short* em = (unsigned short*)d_ws;
    uint4* W1f = (uint4*)((char*)d_ws + (size_t)BS_*T_*2);
    uint4* W2f = W1f + 7*4*64;
    unsigned short* tblh = (unsigned short*)((char*)d_ws + (size_t)BS_*T_*2 + 28672 + 16384);

    prep_tbl<<<dim3((V_*E_/4 + 255)/256), dim3(256), 0, stream>>>(emb_table, (uint2*)tblh);
    prep_w<<<dim3((7*4*64 + 4*4*64)/64), dim3(64), 0, stream>>>(W1, W2, W1f, W2f);
    mlp_kernel<<<dim3(BS_/64), dim3(256), 0, stream>>>(
        inputs, tblh, b1, b2, W1f, W2f, em);
    crf_kernel<<<dim3(B_), dim3(64), 0, stream>>>(
        inputs, tags, em, start_trans, end_trans, transitions, out);
}